// Round 1
// baseline (860.364 us; speedup 1.0000x reference)
//
#include <hip/hip_runtime.h>
#include <stdint.h>

// Problem constants
constexpr int NB = 4;        // batch
constexpr int NT = 4096;     // time
constexpr int NH = 2048;     // hidden
constexpr int MROWS = NB * NT;       // 16384
constexpr int TP1 = NT + 1;          // 4097
constexpr int CHNK = 128;            // time-chunk for LSE scan
constexpr int NCH = 33;              // ceil(4097/128)

typedef unsigned short u16;
typedef __bf16 bf16x8 __attribute__((ext_vector_type(8)));
typedef float f32x4 __attribute__((ext_vector_type(4)));
typedef unsigned short u16x8 __attribute__((ext_vector_type(8)));

__device__ __forceinline__ u16 f2bf(float f) {
  unsigned int u = __float_as_uint(f);
  return (u16)((u + 0x7fffu + ((u >> 16) & 1u)) >> 16);
}
__device__ __forceinline__ float sp_(float x) {          // softplus, stable
  return fmaxf(x, 0.f) + log1pf(expf(-fabsf(x)));
}
__device__ __forceinline__ float glog_(float x) {        // g_log, G_EPS=0.5
  return (x >= 0.f) ? logf(x + 0.5f) : -sp_(-x);
}
__device__ __forceinline__ void gld16(const void* g, void* l) {
  __builtin_amdgcn_global_load_lds((const __attribute__((address_space(1))) void*)g,
                                   (__attribute__((address_space(3))) void*)l, 16, 0, 0);
}

// ---------------- K0: fp32 -> bf16 convert (vectorized) ----------------
__global__ __launch_bounds__(256) void cvt_bf16(const float* __restrict__ in,
                                                u16* __restrict__ out, int n8) {
  int i = blockIdx.x * 256 + threadIdx.x;
  if (i >= n8) return;
  const float4* p = (const float4*)in;
  float4 a = p[2 * i], b = p[2 * i + 1];
  u16x8 o;
  o[0] = f2bf(a.x); o[1] = f2bf(a.y); o[2] = f2bf(a.z); o[3] = f2bf(a.w);
  o[4] = f2bf(b.x); o[5] = f2bf(b.y); o[6] = f2bf(b.z); o[7] = f2bf(b.w);
  *(u16x8*)(out + (size_t)i * 8) = o;
}

// ---------------- K1: bf16 MFMA GEMM, C = A @ Wm^T + bias (m97 structure) ----
// A: [MROWS, NH] bf16 row-major. Wm: [NH, NH] bf16 row-major (B^T layout).
// blockIdx.y selects (Wz -> Ck) or (Wh -> Cu). 128x128 tile, BK=64, 4 waves.
__global__ __launch_bounds__(256) void gemm_bt(
    const u16* __restrict__ A,
    const u16* __restrict__ Bz, const u16* __restrict__ Bh,
    const float* __restrict__ bz, const float* __restrict__ bh,
    float* __restrict__ Ck, float* __restrict__ Cu) {
  const u16* Bm  = blockIdx.y ? Bh : Bz;
  const float* bias = blockIdx.y ? bh : bz;
  float* C = blockIdx.y ? Cu : Ck;

  const int bx = blockIdx.x & 15;   // N tile (16)
  const int by = blockIdx.x >> 4;   // M tile (128)
  const int row0 = by << 7, col0 = bx << 7;

  __shared__ u16 ldsA[128 * 64];
  __shared__ u16 ldsB[128 * 64];

  const int tid = threadIdx.x;
  const int lane = tid & 63;
  const int wv = tid >> 6;
  const int wr = (wv >> 1) << 6;    // wave row offset: 0 / 64
  const int wc = (wv & 1) << 6;     // wave col offset: 0 / 64

  f32x4 acc[4][4] = {};

  for (int k0 = 0; k0 < NH; k0 += 64) {
    if (k0) __syncthreads();
#pragma unroll
    for (int i = 0; i < 4; ++i) {
      const int fo = (i * 256 + tid) << 4;  // byte offset in 16KB tile
      const int r = fo >> 7;                // row (128B per row)
      const int c = (fo & 127) >> 1;        // bf16 col
      gld16(A  + (size_t)(row0 + r) * NH + (k0 + c), &ldsA[(size_t)(i * 256 + wv * 64) * 8]);
      gld16(Bm + (size_t)(col0 + r) * NH + (k0 + c), &ldsB[(size_t)(i * 256 + wv * 64) * 8]);
    }
    __syncthreads();
#pragma unroll
    for (int ks = 0; ks < 2; ++ks) {
      bf16x8 af[4], bfr[4];
#pragma unroll
      for (int m = 0; m < 4; ++m)
        af[m] = *(const bf16x8*)&ldsA[(wr + m * 16 + (lane & 15)) * 64 + ks * 32 + (lane >> 4) * 8];
#pragma unroll
      for (int n = 0; n < 4; ++n)
        bfr[n] = *(const bf16x8*)&ldsB[(wc + n * 16 + (lane & 15)) * 64 + ks * 32 + (lane >> 4) * 8];
#pragma unroll
      for (int m = 0; m < 4; ++m)
#pragma unroll
        for (int n = 0; n < 4; ++n)
          acc[m][n] = __builtin_amdgcn_mfma_f32_16x16x32_bf16(af[m], bfr[n], acc[m][n], 0, 0, 0);
    }
  }

  const int fr = lane & 15, fq = lane >> 4;
#pragma unroll
  for (int n = 0; n < 4; ++n) {
    const int col = col0 + wc + n * 16 + fr;
    const float bv = bias[col];
#pragma unroll
    for (int m = 0; m < 4; ++m) {
#pragma unroll
      for (int v = 0; v < 4; ++v) {
        const int row = row0 + wr + m * 16 + fq * 4 + v;
        C[(size_t)row * NH + col] = acc[m][n][v] + bv;
      }
    }
  }
}

// ---------------- K2: pointwise + inclusive cumsum over hidden -------------
// In-place: KA row r: k -> a_star[b, r%NT + 1]; UD row r: u -> d = lv - a_star.
__global__ __launch_bounds__(256) void rowcum(float* __restrict__ KA,
                                              float* __restrict__ UD) {
  const int r = blockIdx.x;
  const int tid = threadIdx.x;
  const size_t off = (size_t)r * NH + tid * 8;

  float4 k0 = *(const float4*)(KA + off);
  float4 k1 = *(const float4*)(KA + off + 4);
  float4 u0 = *(const float4*)(UD + off);
  float4 u1 = *(const float4*)(UD + off + 4);
  float kk[8] = {k0.x, k0.y, k0.z, k0.w, k1.x, k1.y, k1.z, k1.w};
  float uu[8] = {u0.x, u0.y, u0.z, u0.w, u1.x, u1.y, u1.z, u1.w};

  float lv[8], cum[8];
  float run = 0.f;
#pragma unroll
  for (int e = 0; e < 8; ++e) {
    float kv = kk[e];
    float lc = -sp_(kv);                 // log(1 - sigmoid(k))
    lv[e] = -sp_(-kv) + glog_(uu[e]);    // log sigmoid(k) + g_log(u)
    run += lc;
    cum[e] = run;
  }
  // block-wide exclusive prefix of per-thread totals
  const int lane = tid & 63, wv = tid >> 6;
  float v = run;
#pragma unroll
  for (int d = 1; d < 64; d <<= 1) {
    float o = __shfl_up(v, d, 64);
    if (lane >= d) v += o;
  }
  __shared__ float wsum[4];
  if (lane == 63) wsum[wv] = v;
  __syncthreads();
  float base = v - run;
#pragma unroll
  for (int w = 0; w < 4; ++w)
    if (w < wv) base += wsum[w];

  float4 a0, a1, d0, d1;
  float as[8], dd[8];
#pragma unroll
  for (int e = 0; e < 8; ++e) {
    as[e] = base + cum[e];
    dd[e] = lv[e] - as[e];
  }
  a0.x = as[0]; a0.y = as[1]; a0.z = as[2]; a0.w = as[3];
  a1.x = as[4]; a1.y = as[5]; a1.z = as[6]; a1.w = as[7];
  d0.x = dd[0]; d0.y = dd[1]; d0.z = dd[2]; d0.w = dd[3];
  d1.x = dd[4]; d1.y = dd[5]; d1.z = dd[6]; d1.w = dd[7];
  *(float4*)(KA + off)     = a0;
  *(float4*)(KA + off + 4) = a1;
  *(float4*)(UD + off)     = d0;
  *(float4*)(UD + off + 4) = d1;
}

// ---------------- K3: chunked online cumulative-logsumexp over time --------
// DL holds d (time tt stored at row b*NT + tt-1); writes local LSE L in-place.
// tt==0 row is computed on the fly from h0 and written to Z0.
__global__ __launch_bounds__(256) void timescan(float* __restrict__ DL,
                                                float* __restrict__ Z0,
                                                float* __restrict__ cm,
                                                float* __restrict__ cs,
                                                const float* __restrict__ h0) {
  const int ch = blockIdx.x;
  const int b = blockIdx.y >> 3;
  const int hh = ((blockIdx.y & 7) << 8) + threadIdx.x;
  int t0 = ch * CHNK;
  int t1 = t0 + CHNK; if (t1 > TP1) t1 = TP1;

  float m = -INFINITY, s = 0.f;
  for (int tt = t0; tt < t1; ++tt) {
    if (tt == 0) {
      float x = glog_(h0[hh]);
      m = x; s = 1.f;
      Z0[(size_t)b * NH + hh] = x;
    } else {
      size_t off = ((size_t)b * NT + (tt - 1)) * NH + hh;
      float x = DL[off];
      float nm = fmaxf(m, x);
      s = s * expf(m - nm) + expf(x - nm);
      m = nm;
      DL[off] = m + logf(s);
    }
  }
  size_t co = ((size_t)ch * NB + b) * NH + hh;
  cm[co] = m;
  cs[co] = s;
}

// ---------------- K4: exclusive scan of chunk carries over chunks ----------
__global__ __launch_bounds__(256) void carryscan(const float* __restrict__ cm,
                                                 const float* __restrict__ cs,
                                                 float* __restrict__ em,
                                                 float* __restrict__ es) {
  int c = blockIdx.x * 256 + threadIdx.x;   // 0..NB*NH-1
  int b = c >> 11;
  int hh = c & (NH - 1);
  float Cm = -INFINITY, Cs = 0.f;
  for (int ch = 0; ch < NCH; ++ch) {
    size_t o = ((size_t)ch * NB + b) * NH + hh;
    em[o] = Cm; es[o] = Cs;
    float m2 = cm[o], s2 = cs[o];
    float M = fmaxf(Cm, m2);
    Cs = Cs * expf(Cm - M) + s2 * expf(m2 - M);
    Cm = M;
  }
}

// ---------------- K5: combine carries, add a_star, global stats ------------
__global__ __launch_bounds__(256) void combine_stats(
    float* __restrict__ DL, const float* __restrict__ Z0,
    const float* __restrict__ em, const float* __restrict__ es,
    const float* __restrict__ AS, double* __restrict__ sums) {
  const int ch = blockIdx.x;
  const int b = blockIdx.y >> 3;
  const int hh = ((blockIdx.y & 7) << 8) + threadIdx.x;
  size_t co = ((size_t)ch * NB + b) * NH + hh;
  const float Cm = em[co], Cs = es[co];
  int t0 = ch * CHNK;
  int t1 = t0 + CHNK; if (t1 > TP1) t1 = TP1;

  double s1 = 0.0, s2 = 0.0;
  for (int tt = t0; tt < t1; ++tt) {
    float L, as;
    size_t off = 0;
    bool wr = (tt != 0);
    if (wr) {
      off = ((size_t)b * NT + (tt - 1)) * NH + hh;
      L = DL[off];
      as = AS[off];
    } else {
      L = Z0[(size_t)b * NH + hh];
      as = 0.f;
    }
    float M = fmaxf(L, Cm);
    float lse = M + logf(expf(L - M) + Cs * expf(Cm - M));
    float lh = as + lse;
    if (wr) DL[off] = lh;
    s1 += (double)lh;
    s2 += (double)lh * (double)lh;
  }
  // block reduce (doubles) -> device atomics
  double v1 = s1, v2 = s2;
#pragma unroll
  for (int d = 32; d; d >>= 1) {
    v1 += __shfl_down(v1, d, 64);
    v2 += __shfl_down(v2, d, 64);
  }
  __shared__ double dr1[4], dr2[4];
  const int lane = threadIdx.x & 63, wv = threadIdx.x >> 6;
  if (lane == 0) { dr1[wv] = v1; dr2[wv] = v2; }
  __syncthreads();
  if (threadIdx.x == 0) {
    atomicAdd(&sums[0], dr1[0] + dr1[1] + dr1[2] + dr1[3]);
    atomicAdd(&sums[1], dr2[0] + dr2[1] + dr2[2] + dr2[3]);
  }
}

// ---------------- K6: finalize global mean / inv-std (ddof=1) --------------
__global__ void finalize_stats(const double* __restrict__ sums,
                               float* __restrict__ stats) {
  double S = sums[0], S2 = sums[1];
  const double N = (double)NB * (double)TP1 * (double)NH;
  double mu = S / N;
  double var = (S2 - S * S / N) / (N - 1.0);
  stats[0] = (float)mu;
  stats[1] = (float)(1.0 / sqrt(var));
}

// ---------------- K7: exp + residual + LayerNorm ---------------------------
// DL row r holds log_h[b, t+1]; output written in place (DL == d_out).
__global__ __launch_bounds__(256) void final_ln(float* __restrict__ DL,
                                                const float* __restrict__ hs,
                                                const float* __restrict__ lnw,
                                                const float* __restrict__ lnb,
                                                const float* __restrict__ stats) {
  const int tid = threadIdx.x;
  const size_t off = (size_t)blockIdx.x * NH + tid * 8;
  const float mu_g = stats[0], isd = stats[1];

  float4 l0 = *(const float4*)(DL + off);
  float4 l1 = *(const float4*)(DL + off + 4);
  float4 a0 = *(const float4*)(hs + off);
  float4 a1 = *(const float4*)(hs + off + 4);
  float lh[8] = {l0.x, l0.y, l0.z, l0.w, l1.x, l1.y, l1.z, l1.w};
  float av[8] = {a0.x, a0.y, a0.z, a0.w, a1.x, a1.y, a1.z, a1.w};
  float x[8];
  float s = 0.f, q = 0.f;
#pragma unroll
  for (int e = 0; e < 8; ++e) {
    x[e] = expf((lh[e] - mu_g) * isd) + av[e];
    s += x[e];
    q += x[e] * x[e];
  }
#pragma unroll
  for (int d = 32; d; d >>= 1) {
    s += __shfl_down(s, d, 64);
    q += __shfl_down(q, d, 64);
  }
  __shared__ float r1[4], r2[4];
  const int lane = tid & 63, wv = tid >> 6;
  if (lane == 0) { r1[wv] = s; r2[wv] = q; }
  __syncthreads();
  float st = r1[0] + r1[1] + r1[2] + r1[3];
  float qt = r2[0] + r2[1] + r2[2] + r2[3];
  const float mean = st * (1.0f / NH);
  const float var = qt * (1.0f / NH) - mean * mean;
  const float rstd = rsqrtf(var + 1e-5f);

  float4 w0 = *(const float4*)(lnw + tid * 8);
  float4 w1 = *(const float4*)(lnw + tid * 8 + 4);
  float4 b0 = *(const float4*)(lnb + tid * 8);
  float4 b1 = *(const float4*)(lnb + tid * 8 + 4);
  float wv8[8] = {w0.x, w0.y, w0.z, w0.w, w1.x, w1.y, w1.z, w1.w};
  float bv8[8] = {b0.x, b0.y, b0.z, b0.w, b1.x, b1.y, b1.z, b1.w};
  float o[8];
#pragma unroll
  for (int e = 0; e < 8; ++e)
    o[e] = (x[e] - mean) * rstd * wv8[e] + bv8[e];
  float4 o0, o1;
  o0.x = o[0]; o0.y = o[1]; o0.z = o[2]; o0.w = o[3];
  o1.x = o[4]; o1.y = o[5]; o1.z = o[6]; o1.w = o[7];
  *(float4*)(DL + off)     = o0;
  *(float4*)(DL + off + 4) = o1;
}

extern "C" void kernel_launch(void* const* d_in, const int* in_sizes, int n_in,
                              void* d_out, int out_size, void* d_ws, size_t ws_size,
                              hipStream_t stream) {
  (void)in_sizes; (void)n_in; (void)out_size; (void)ws_size;
  const float* hs  = (const float*)d_in[0];
  const float* Wz  = (const float*)d_in[1];
  const float* bz  = (const float*)d_in[2];
  const float* Wh  = (const float*)d_in[3];
  const float* bh  = (const float*)d_in[4];
  const float* lnw = (const float*)d_in[5];
  const float* lnb = (const float*)d_in[6];
  const float* h0  = (const float*)d_in[7];
  float* out = (float*)d_out;

  // workspace carve (~212 MiB)
  char* w = (char*)d_ws;
  u16* hsb   = (u16*)w;  w += (size_t)MROWS * NH * 2;       // 64 MiB
  u16* wzb   = (u16*)w;  w += (size_t)NH * NH * 2;          // 8 MiB
  u16* whb   = (u16*)w;  w += (size_t)NH * NH * 2;          // 8 MiB
  float* kbuf = (float*)w; w += (size_t)MROWS * NH * 4;     // 128 MiB (k -> a_star)
  float* Z0   = (float*)w; w += (size_t)NB * NH * 4;
  float* cm_  = (float*)w; w += (size_t)NCH * NB * NH * 4;
  float* cs_  = (float*)w; w += (size_t)NCH * NB * NH * 4;
  float* em_  = (float*)w; w += (size_t)NCH * NB * NH * 4;
  float* es_  = (float*)w; w += (size_t)NCH * NB * NH * 4;
  double* sums = (double*)w; w += 16;
  float* stats = (float*)w;  w += 16;

  hipMemsetAsync(sums, 0, 16, stream);

  // K0: convert inputs to bf16
  cvt_bf16<<<dim3((MROWS * NH / 8 + 255) / 256), 256, 0, stream>>>(hs, hsb, MROWS * NH / 8);
  cvt_bf16<<<dim3((NH * NH / 8 + 255) / 256), 256, 0, stream>>>(Wz, wzb, NH * NH / 8);
  cvt_bf16<<<dim3((NH * NH / 8 + 255) / 256), 256, 0, stream>>>(Wh, whb, NH * NH / 8);

  // K1: k = hs@Wz^T + bz -> kbuf ; u = hs@Wh^T + bh -> d_out (scratch)
  gemm_bt<<<dim3((MROWS / 128) * (NH / 128), 2), 256, 0, stream>>>(
      hsb, wzb, whb, bz, bh, kbuf, out);

  // K2: pointwise + hidden-dim cumsum (in-place: kbuf -> a_star, out -> d)
  rowcum<<<dim3(MROWS), 256, 0, stream>>>(kbuf, out);

  // K3..K5: chunked cumulative logsumexp over time + global stats
  timescan<<<dim3(NCH, 32), 256, 0, stream>>>(out, Z0, cm_, cs_, h0);
  carryscan<<<dim3(NB * NH / 256), 256, 0, stream>>>(cm_, cs_, em_, es_);
  combine_stats<<<dim3(NCH, 32), 256, 0, stream>>>(out, Z0, em_, es_, kbuf, sums);
  finalize_stats<<<1, 1, 0, stream>>>(sums, stats);

  // K7: h = exp(norm(log_h)); x = h + hs; LayerNorm -> d_out (in place)
  final_ln<<<dim3(MROWS), 256, 0, stream>>>(out, hs, lnw, lnb, stats);
}